// Round 6
// baseline (434.979 us; speedup 1.0000x reference)
//
#include <hip/hip_runtime.h>

#define B_ 1024
#define D_ 784
#define H_ 1024
#define BH_ (B_ * H_)
#define LOG2E 1.4426950408889634f

// Segments: {0,200,400,592,784}. G ranges: [0,200),[200,400),[400,592).
// ws: Wt [D][H] 3.21 MB | G [3][B][H] 12.6 MB | part [8][B][D] 25.7 MB

typedef float v2f __attribute__((ext_vector_type(2)));
__device__ __forceinline__ v2f vfma(v2f a, v2f b, v2f c) {
    return __builtin_elementwise_fma(a, b, c);
}

// ---------- fat prep: blocks [0,800) transpose W; [800,1568) partial GEMMs ----------
__global__ __launch_bounds__(256) void prep(const float* __restrict__ W,
                                            const float* __restrict__ px,
                                            float* __restrict__ Wt,
                                            float* __restrict__ G) {
    __shared__ float smem[32 * 33];
    const int t = threadIdx.x;

    if (blockIdx.x < 800) {
        // Wt[i*H+h] = W[h*D+i] * log2e
        int i0 = (blockIdx.x % 25) * 32;
        int h0 = (blockIdx.x / 25) * 32;
        int tx = t & 31, ty = t >> 5;   // 32 x 8
#pragma unroll
        for (int j = 0; j < 4; ++j) {
            int h = h0 + ty + j * 8;
            int i = i0 + tx;
            float v = 0.f;
            if (i < D_) v = W[(size_t)h * D_ + i] * LOG2E;
            smem[(ty + j * 8) * 33 + tx] = v;
        }
        __syncthreads();
#pragma unroll
        for (int j = 0; j < 4; ++j) {
            int i = i0 + ty + j * 8;
            int h = h0 + tx;
            if (i < D_) Wt[(size_t)i * H_ + h] = smem[tx * 33 + ty + j * 8];
        }
    } else {
        // G[r][b][h] = sum_{j in range r} px[b][j] * W[h][j] * log2e
        float* xs = smem;          // [4][64]
        float* ws = smem + 256;    // [4][64]
        int idx = blockIdx.x - 800;
        int r   = idx >> 8;                       // 0..2
        int b0  = (idx & 15) * 64;
        int h0  = ((idx >> 4) & 15) * 64;
        const int lo[3] = {0, 200, 400};
        const int hi[3] = {200, 400, 592};
        int j0s = lo[r], j1s = hi[r];

        const int tb = t >> 4, th = t & 15;       // 16x16, each 4b x 4h
        float acc[4][4];
#pragma unroll
        for (int bi = 0; bi < 4; ++bi)
#pragma unroll
            for (int hh = 0; hh < 4; ++hh) acc[bi][hh] = 0.f;

        for (int j0 = j0s; j0 < j1s; j0 += 4) {
            float xv = px[(size_t)(b0 + (t >> 2)) * D_ + j0 + (t & 3)];
            float4 wv = make_float4(0, 0, 0, 0);
            if (t < 64) wv = *(const float4*)(W + (size_t)(h0 + t) * D_ + j0);
            __syncthreads();
            xs[(t & 3) * 64 + (t >> 2)] = xv;
            if (t < 64) {
                ws[0 * 64 + t] = wv.x * LOG2E;
                ws[1 * 64 + t] = wv.y * LOG2E;
                ws[2 * 64 + t] = wv.z * LOG2E;
                ws[3 * 64 + t] = wv.w * LOG2E;
            }
            __syncthreads();
#pragma unroll
            for (int jj = 0; jj < 4; ++jj) {
                float4 xb = *(float4*)&xs[jj * 64 + tb * 4];
                float4 wb = *(float4*)&ws[jj * 64 + th * 4];
                float xa[4] = {xb.x, xb.y, xb.z, xb.w};
                float wa[4] = {wb.x, wb.y, wb.z, wb.w};
#pragma unroll
                for (int bi = 0; bi < 4; ++bi)
#pragma unroll
                    for (int hh = 0; hh < 4; ++hh)
                        acc[bi][hh] = fmaf(xa[bi], wa[hh], acc[bi][hh]);
            }
        }
        float* dst = G + (size_t)r * BH_;
#pragma unroll
        for (int bi = 0; bi < 4; ++bi) {
            float4 o = make_float4(acc[bi][0], acc[bi][1], acc[bi][2], acc[bi][3]);
            *(float4*)(dst + (size_t)(b0 + tb * 4 + bi) * H_ + h0 + th * 4) = o;
        }
    }
}

// ---------- DPP reduce: both 32-lane halves simultaneously ----------
template <int CTRL>
__device__ __forceinline__ float dpp_add(float p) {
    int s = __builtin_amdgcn_update_dpp(0, __float_as_int(p), CTRL, 0xf, 0xf, true);
    return p + __int_as_float(s);
}
__device__ __forceinline__ float reduce_halves(float p) {
    p = dpp_add<0x111>(p);
    p = dpp_add<0x112>(p);
    p = dpp_add<0x114>(p);
    p = dpp_add<0x118>(p);
    p = dpp_add<0x142>(p);   // lane31 = sum(0..31), lane63 = sum(32..63)
    return p;
}

// ---------- packed software exp2 (t pre-clamped to [-126, 15]) ----------
__device__ __forceinline__ v2f exp2_pair(v2f t) {
    const float MG = 12582912.f;                 // 1.5 * 2^23
    v2f m, n, f, p;
    m = t + (v2f){MG, MG};
    n = m - (v2f){MG, MG};
    f = t - n;
    p = (v2f){0.0013333558f, 0.0013333558f};
    p = vfma(p, f, (v2f){0.0096181291f, 0.0096181291f});
    p = vfma(p, f, (v2f){0.0555041087f, 0.0555041087f});
    p = vfma(p, f, (v2f){0.2402265070f, 0.2402265070f});
    p = vfma(p, f, (v2f){0.6931471806f, 0.6931471806f});
    p = vfma(p, f, (v2f){1.0f, 1.0f});
    unsigned b0 = (__float_as_uint(m.x) << 23) + 0x3F800000u;   // 2^n bits
    unsigned b1 = (__float_as_uint(m.y) << 23) + 0x3F800000u;
    v2f s = {__uint_as_float(b0), __uint_as_float(b1)};
    return s * p;
}

// ---------- main scan: 4 segments x 8 hb x 512 row-pairs = 16384 waves, 4 h/lane ----------
__global__ __launch_bounds__(256, 8) void nade_main(
    const float* __restrict__ px,   // [B, D]
    const float* __restrict__ c,    // [H]
    const float* __restrict__ V,    // [D, H] (used directly)
    const float* __restrict__ Wt,   // [D, H] * log2e
    const float* __restrict__ G,    // [3][B][H] partial-range GEMMs (log2 domain)
    float* __restrict__ part)       // [8][B][D]
{
    const int lane = threadIdx.x & 63;
    const int wid  = threadIdx.x >> 6;
    const int gw   = blockIdx.x * 4 + wid;   // 0..16383
    const int s    = gw & 3;
    const int hb   = (gw >> 2) & 7;
    const int rp   = gw >> 5;                // 0..511
    const int half = lane >> 5;
    const int row  = rp * 2 + half;
    const int hl   = lane & 31;
    const int h0   = hb * 128 + hl * 4;

    const int lo[4] = {0, 200, 400, 592};
    const int hi4[4] = {200, 400, 592, 784};
    const int i0s = lo[s], i1s = hi4[s];

    // A (log2 domain) = c*log2e + sum_{r<s} G_r
    v2f A01, A23;
    {
        float4 c0 = *(const float4*)(c + h0);
        A01.x = c0.x * LOG2E; A01.y = c0.y * LOG2E;
        A23.x = c0.z * LOG2E; A23.y = c0.w * LOG2E;
        for (int r = 0; r < s; ++r) {
            float4 g = *(const float4*)(G + (size_t)r * BH_ + (size_t)row * H_ + h0);
            A01.x += g.x; A01.y += g.y; A23.x += g.z; A23.y += g.w;
        }
    }

    const float* xp = px + (size_t)row * D_;
    float*       pp = part + ((size_t)hb * B_ + row) * D_;

    // one step: software exp2 pairs + exact grouped rcp over 4
    auto step4 = [&](const float4& v4, const float4& w4, float xi) -> float {
        v2f t0, t1;
        t0.x = __builtin_amdgcn_fmed3f(-A01.x, -126.f, 15.f);
        t0.y = __builtin_amdgcn_fmed3f(-A01.y, -126.f, 15.f);
        t1.x = __builtin_amdgcn_fmed3f(-A23.x, -126.f, 15.f);
        t1.y = __builtin_amdgcn_fmed3f(-A23.y, -126.f, 15.f);
        v2f e0 = exp2_pair(t0);
        v2f e1 = exp2_pair(t1);
        v2f one = {1.f, 1.f};
        v2f q0 = e0 + one;
        v2f q1 = e1 + one;
        v2f x2 = {xi, xi};
        A01 = vfma((v2f){w4.x, w4.y}, x2, A01);
        A23 = vfma((v2f){w4.z, w4.w}, x2, A23);
        float a01 = fmaf(v4.x, q0.y, v4.y * q0.x);
        float a23 = fmaf(v4.z, q1.y, v4.w * q1.x);
        float q01 = q0.x * q0.y, q23 = q1.x * q1.y;
        float r = __builtin_amdgcn_rcpf(q01 * q23);
        float n = fmaf(a01, q23, a23 * q01);
        return n * r;
    };

    float4 vv = *(const float4*)(V  + (size_t)i0s * H_ + h0);
    float4 ww = *(const float4*)(Wt + (size_t)i0s * H_ + h0);

    // main blocks: unconditional next-step prefetch
    int ib = i0s;
    for (; ib < i1s - 4; ib += 4) {
        float4 xq = *(const float4*)(xp + ib);
        float xa[4] = {xq.x, xq.y, xq.z, xq.w};
        float pr[4];
#pragma unroll
        for (int j = 0; j < 4; ++j) {
            const float* vn_p = V  + (size_t)(ib + j + 1) * H_ + h0;
            const float* wn_p = Wt + (size_t)(ib + j + 1) * H_ + h0;
            float4 vn = *(const float4*)vn_p;
            float4 wn = *(const float4*)wn_p;
            float p = step4(vv, ww, xa[j]);
            pr[j] = reduce_halves(p);
            vv = vn; ww = wn;
        }
        if (hl == 31) *(float4*)(pp + ib) = make_float4(pr[0], pr[1], pr[2], pr[3]);
    }
    // epilogue block: clamped prefetch (avoids OOB at i1s == D_)
    {
        float4 xq = *(const float4*)(xp + ib);
        float xa[4] = {xq.x, xq.y, xq.z, xq.w};
        float pr[4];
#pragma unroll
        for (int j = 0; j < 4; ++j) {
            int inext = ib + j + 1; if (inext >= i1s) inext = i1s - 1;
            float4 vn = *(const float4*)(V  + (size_t)inext * H_ + h0);
            float4 wn = *(const float4*)(Wt + (size_t)inext * H_ + h0);
            float p = step4(vv, ww, xa[j]);
            pr[j] = reduce_halves(p);
            vv = vn; ww = wn;
        }
        if (hl == 31) *(float4*)(pp + ib) = make_float4(pr[0], pr[1], pr[2], pr[3]);
    }
}

// ---------- epilogue: out[row][i] = bias[i] + sum_hb part[hb][row][i] ----------
__global__ __launch_bounds__(256) void reduce_out(const float* __restrict__ part,
                                                  const float* __restrict__ bias,
                                                  float* __restrict__ out) {
    int t = blockIdx.x * 256 + threadIdx.x;
    if (t >= B_ * (D_ / 4)) return;
    int row = t / (D_ / 4);
    int ic  = (t - row * (D_ / 4)) * 4;
    float4 acc = *(const float4*)(bias + ic);
    const float* p = part + (size_t)row * D_ + ic;
#pragma unroll
    for (int hb = 0; hb < 8; ++hb) {
        float4 v = *(const float4*)(p + (size_t)hb * B_ * D_);
        acc.x += v.x; acc.y += v.y; acc.z += v.z; acc.w += v.w;
    }
    *(float4*)(out + (size_t)row * D_ + ic) = acc;
}

extern "C" void kernel_launch(void* const* d_in, const int* in_sizes, int n_in,
                              void* d_out, int out_size, void* d_ws, size_t ws_size,
                              hipStream_t stream) {
    const float* px   = (const float*)d_in[0];  // [B, D]
    const float* W    = (const float*)d_in[1];  // [H, D]
    const float* c    = (const float*)d_in[2];  // [H]
    const float* V    = (const float*)d_in[3];  // [D, H]
    const float* bias = (const float*)d_in[4];  // [D]
    float* out = (float*)d_out;                 // [B, D]

    float* Wt   = (float*)d_ws;                 // [D][H]
    float* G    = Wt + (size_t)D_ * H_;         // [3][B][H]
    float* part = G + (size_t)3 * BH_;          // [8][B][D]

    prep<<<dim3(1568), 256, 0, stream>>>(W, px, Wt, G);

    // 4096 blocks x 4 waves = 16384 waves (2 residency rounds)
    nade_main<<<dim3(4096), 256, 0, stream>>>(px, c, V, Wt, G, part);

    reduce_out<<<dim3((B_ * (D_ / 4) + 255) / 256), 256, 0, stream>>>(part, bias, out);
}

// Round 7
// 319.933 us; speedup vs baseline: 1.3596x; 1.3596x over previous
//
#include <hip/hip_runtime.h>

#define B_ 1024
#define D_ 784
#define H_ 1024
#define BH_ (B_ * H_)
#define LOG2E 1.4426950408889634f

// Segments: {0,132,264,396,528,656,784}; G ranges: first 5 of those spans.
// ws: VW [788][4][512] interleaved (V|W*log2e) 6.45 MB | G [5][B][H] 21 MB | part [4][B][D] 12.8 MB

__device__ __forceinline__ int seg_bound(int s) {
    const int b[7] = {0, 132, 264, 396, 528, 656, 784};
    return b[s];
}

// ---------- fat prep ----------
// blocks [0,800):    build VW interleaved (V copy + W transpose*log2e), 32i x 32h tiles
// blocks [800,2080): G[r][b][h] = sum_{j in range r} px[b][j]*W[h][j]*log2e  (r<5)
__global__ __launch_bounds__(256) void prep(const float* __restrict__ V,
                                            const float* __restrict__ W,
                                            const float* __restrict__ px,
                                            float* __restrict__ VW,
                                            float* __restrict__ G) {
    __shared__ float smem[32 * 33];
    const int t = threadIdx.x;

    if (blockIdx.x < 800) {
        int i0 = (blockIdx.x % 25) * 32;
        int h0 = (blockIdx.x / 25) * 32;
        int tx = t & 31, ty = t >> 5;   // 32 x 8
        int hb = h0 >> 8, hl = h0 & 255;
        // V copy
#pragma unroll
        for (int j = 0; j < 4; ++j) {
            int i = i0 + ty + j * 8;
            if (i < D_)
                VW[((size_t)i * 4 + hb) * 512 + hl + tx] = V[(size_t)i * H_ + h0 + tx];
        }
        // W transpose via LDS, *log2e
#pragma unroll
        for (int j = 0; j < 4; ++j) {
            int h = h0 + ty + j * 8;
            int i = i0 + tx;
            float v = 0.f;
            if (i < D_) v = W[(size_t)h * D_ + i] * LOG2E;
            smem[(ty + j * 8) * 33 + tx] = v;
        }
        __syncthreads();
#pragma unroll
        for (int j = 0; j < 4; ++j) {
            int i = i0 + ty + j * 8;
            if (i < D_)
                VW[((size_t)i * 4 + hb) * 512 + 256 + hl + tx] = smem[tx * 33 + ty + j * 8];
        }
    } else {
        float* xs = smem;          // [4][64]
        float* ws = smem + 256;    // [4][64]
        int idx = blockIdx.x - 800;
        int r   = idx >> 8;                       // 0..4
        int b0  = (idx & 15) * 64;
        int h0  = ((idx >> 4) & 15) * 64;
        int j0s = seg_bound(r), j1s = seg_bound(r + 1);

        const int tb = t >> 4, th = t & 15;       // 16x16, each 4b x 4h
        float acc[4][4];
#pragma unroll
        for (int bi = 0; bi < 4; ++bi)
#pragma unroll
            for (int hh = 0; hh < 4; ++hh) acc[bi][hh] = 0.f;

        for (int j0 = j0s; j0 < j1s; j0 += 4) {
            float xv = px[(size_t)(b0 + (t >> 2)) * D_ + j0 + (t & 3)];
            float4 wv = make_float4(0, 0, 0, 0);
            if (t < 64) wv = *(const float4*)(W + (size_t)(h0 + t) * D_ + j0);
            __syncthreads();
            xs[(t & 3) * 64 + (t >> 2)] = xv;
            if (t < 64) {
                ws[0 * 64 + t] = wv.x * LOG2E;
                ws[1 * 64 + t] = wv.y * LOG2E;
                ws[2 * 64 + t] = wv.z * LOG2E;
                ws[3 * 64 + t] = wv.w * LOG2E;
            }
            __syncthreads();
#pragma unroll
            for (int jj = 0; jj < 4; ++jj) {
                float4 xb = *(float4*)&xs[jj * 64 + tb * 4];
                float4 wb = *(float4*)&ws[jj * 64 + th * 4];
                float xa[4] = {xb.x, xb.y, xb.z, xb.w};
                float wa[4] = {wb.x, wb.y, wb.z, wb.w};
#pragma unroll
                for (int bi = 0; bi < 4; ++bi)
#pragma unroll
                    for (int hh = 0; hh < 4; ++hh)
                        acc[bi][hh] = fmaf(xa[bi], wa[hh], acc[bi][hh]);
            }
        }
        float* dst = G + (size_t)r * BH_;
#pragma unroll
        for (int bi = 0; bi < 4; ++bi) {
            float4 o = make_float4(acc[bi][0], acc[bi][1], acc[bi][2], acc[bi][3]);
            *(float4*)(dst + (size_t)(b0 + tb * 4 + bi) * H_ + h0 + th * 4) = o;
        }
    }
}

// ---------- DPP reduce: both 32-lane halves simultaneously ----------
template <int CTRL>
__device__ __forceinline__ float dpp_add(float p) {
    int s = __builtin_amdgcn_update_dpp(0, __float_as_int(p), CTRL, 0xf, 0xf, true);
    return p + __int_as_float(s);
}
__device__ __forceinline__ float reduce_halves(float p) {
    p = dpp_add<0x111>(p);
    p = dpp_add<0x112>(p);
    p = dpp_add<0x114>(p);
    p = dpp_add<0x118>(p);
    p = dpp_add<0x142>(p);   // lane31 = sum(0..31), lane63 = sum(32..63)
    return p;
}

// ---------- main scan: 6 segments x 4 hb x 512 row-pairs = 12288 waves, 8 h/lane ----------
__global__ __launch_bounds__(256, 6) void nade_main(
    const float* __restrict__ px,   // [B, D]
    const float* __restrict__ c,    // [H]
    const float* __restrict__ VW,   // [788][4][512] interleaved
    const float* __restrict__ G,    // [5][B][H] partial-range GEMMs (log2 domain)
    float* __restrict__ part)       // [4][B][D]
{
    const int lane = threadIdx.x & 63;
    const int wid  = threadIdx.x >> 6;
    const int gw   = blockIdx.x * 4 + wid;   // 0..12287
    const int s    = gw % 6;
    const int r4   = gw / 6;                 // 0..2047
    const int hb   = r4 & 3;
    const int rp   = r4 >> 2;                // 0..511
    const int half = lane >> 5;
    const int row  = rp * 2 + half;
    const int hl   = lane & 31;
    const int h0   = hb * 256 + hl * 8;

    const int i0s = seg_bound(s), i1s = seg_bound(s + 1);

    // A (log2 domain) = c*log2e + sum_{r<s} G_r
    float A[8];
    {
        float4 c0 = *(const float4*)(c + h0);
        float4 c1 = *(const float4*)(c + h0 + 4);
        A[0] = c0.x * LOG2E; A[1] = c0.y * LOG2E; A[2] = c0.z * LOG2E; A[3] = c0.w * LOG2E;
        A[4] = c1.x * LOG2E; A[5] = c1.y * LOG2E; A[6] = c1.z * LOG2E; A[7] = c1.w * LOG2E;
        for (int r = 0; r < s; ++r) {
            const float* gp = G + (size_t)r * BH_ + (size_t)row * H_ + h0;
            float4 g0 = *(const float4*)(gp);
            float4 g1 = *(const float4*)(gp + 4);
            A[0] += g0.x; A[1] += g0.y; A[2] += g0.z; A[3] += g0.w;
            A[4] += g1.x; A[5] += g1.y; A[6] += g1.z; A[7] += g1.w;
        }
    }

    const float* xp = px + (size_t)row * D_;
    float*       pp = part + ((size_t)hb * B_ + row) * D_;
    const float* vw = VW + ((size_t)i0s * 4 + hb) * 512 + hl * 8;

    // one step (8 h): grouped rcp over 8 q's; clamp exp arg to 15 so prod(q) < 2^120
    auto step8 = [&A](const float4& v0, const float4& v1,
                      const float4& w0, const float4& w1, float xi) -> float {
        float va[8] = {v0.x, v0.y, v0.z, v0.w, v1.x, v1.y, v1.z, v1.w};
        float wa[8] = {w0.x, w0.y, w0.z, w0.w, w1.x, w1.y, w1.z, w1.w};
        float q[8];
#pragma unroll
        for (int k = 0; k < 8; ++k) {
            float e = __builtin_amdgcn_exp2f(fminf(15.f, -A[k]));
            q[k] = 1.f + e;
            A[k] = fmaf(wa[k], xi, A[k]);
        }
        float a01 = fmaf(va[0], q[1], va[1] * q[0]);
        float a23 = fmaf(va[2], q[3], va[3] * q[2]);
        float a45 = fmaf(va[4], q[5], va[5] * q[4]);
        float a67 = fmaf(va[6], q[7], va[7] * q[6]);
        float q01 = q[0] * q[1], q23 = q[2] * q[3];
        float q45 = q[4] * q[5], q67 = q[6] * q[7];
        float n0123 = fmaf(a01, q23, a23 * q01);
        float n4567 = fmaf(a45, q67, a67 * q45);
        float q0123 = q01 * q23, q4567 = q45 * q67;
        float r = __builtin_amdgcn_rcpf(q0123 * q4567);
        float n = fmaf(n0123, q4567, n4567 * q0123);
        return n * r;
    };

    // preload current quad + first x group
    float4 v0 = *(const float4*)(vw + 0),   v1 = *(const float4*)(vw + 4);
    float4 w0 = *(const float4*)(vw + 256), w1 = *(const float4*)(vw + 260);
    vw += 2048;
    float4 xq = *(const float4*)(xp + i0s);

    for (int ib = i0s; ib < i1s; ib += 4) {     // all segment lengths %4 == 0
        int xb = (ib + 4 < i1s) ? (ib + 4) : i0s;
        float4 xq_n = *(const float4*)(xp + xb);
        float xa[4] = {xq.x, xq.y, xq.z, xq.w};
        float pr[4];
#pragma unroll
        for (int j = 0; j < 4; ++j) {
            // prefetch next step's quad (VW padded to 788 steps -> safe at segment end)
            float4 v0n = *(const float4*)(vw + 0),   v1n = *(const float4*)(vw + 4);
            float4 w0n = *(const float4*)(vw + 256), w1n = *(const float4*)(vw + 260);
            vw += 2048;
            float p = step8(v0, v1, w0, w1, xa[j]);
            pr[j] = reduce_halves(p);
            v0 = v0n; v1 = v1n; w0 = w0n; w1 = w1n;
        }
        if (hl == 31) *(float4*)(pp + ib) = make_float4(pr[0], pr[1], pr[2], pr[3]);
        xq = xq_n;
    }
}

// ---------- epilogue: out[row][i] = bias[i] + sum_hb part[hb][row][i] ----------
__global__ __launch_bounds__(256) void reduce_out(const float* __restrict__ part,
                                                  const float* __restrict__ bias,
                                                  float* __restrict__ out) {
    int t = blockIdx.x * 256 + threadIdx.x;
    if (t >= B_ * (D_ / 4)) return;
    int row = t / (D_ / 4);
    int ic  = (t - row * (D_ / 4)) * 4;
    float4 acc = *(const float4*)(bias + ic);
    const float* p = part + (size_t)row * D_ + ic;
#pragma unroll
    for (int hb = 0; hb < 4; ++hb) {
        float4 v = *(const float4*)(p + (size_t)hb * B_ * D_);
        acc.x += v.x; acc.y += v.y; acc.z += v.z; acc.w += v.w;
    }
    *(float4*)(out + (size_t)row * D_ + ic) = acc;
}

extern "C" void kernel_launch(void* const* d_in, const int* in_sizes, int n_in,
                              void* d_out, int out_size, void* d_ws, size_t ws_size,
                              hipStream_t stream) {
    const float* px   = (const float*)d_in[0];  // [B, D]
    const float* W    = (const float*)d_in[1];  // [H, D]
    const float* c    = (const float*)d_in[2];  // [H]
    const float* V    = (const float*)d_in[3];  // [D, H]
    const float* bias = (const float*)d_in[4];  // [D]
    float* out = (float*)d_out;                 // [B, D]

    float* VW   = (float*)d_ws;                 // 788*2048 floats = 6.45 MB (784 + pad)
    float* G    = VW + (size_t)788 * 2048;      // [5][B][H] = 21 MB
    float* part = G + (size_t)5 * BH_;          // [4][B][D] = 12.8 MB

    prep<<<dim3(2080), 256, 0, stream>>>(V, W, px, VW, G);

    // 3072 blocks x 4 waves = 12288 waves = 2 residency rounds at 6 waves/SIMD
    nade_main<<<dim3(3072), 256, 0, stream>>>(px, c, VW, G, part);

    reduce_out<<<dim3((B_ * (D_ / 4) + 255) / 256), 256, 0, stream>>>(part, bias, out);
}